// Round 13
// baseline (64.794 us; speedup 1.0000x reference)
//
#include <hip/hip_runtime.h>
#include <hip/hip_bf16.h>
#include <math.h>

// Problem constants
#define U_   300
#define K_   19
#define FC_  100
#define B_   256
#define L_   1000
#define P_   140     // pooled length
#define EPS_ 1e-5f
#define WLD_ 144     // fc LDS row stride (bf16): 288 B, 16-B aligned

typedef unsigned short ushort_t;
typedef __attribute__((ext_vector_type(8)))  short short8v;   // 8 bf16 = 4 VGPR
typedef __attribute__((ext_vector_type(16))) float f32x16;    // MFMA 32x32 acc

// f32 -> bf16 round-to-nearest-even (bit trick)
__device__ __forceinline__ ushort_t f2bf(float f) {
    union { float f; unsigned u; } a; a.f = f;
    unsigned r = a.u + 0x7fffu + ((a.u >> 16) & 1u);
    return (ushort_t)(r >> 16);
}

// ---------------------------------------------------------------------------
// pack_conv_k: conv weights -> bf16, BN1 scale folded, COALESCED-TILE layout:
//   element offset = nt*2560 + kc*512 + r*16 + half*8 + e
// (u = nt*32 + r, GEMM-k j = kc*16 + half*8 + e, j order = 4*t + d).
// A wave's B-frag load (fixed kc) is 64 lanes x 16 B contiguous = 2 KB.
// ---------------------------------------------------------------------------
__global__ __launch_bounds__(256, 4)
void pack_conv_k(const float* __restrict__ w_conv, const float* __restrict__ b_conv,
                 const float* __restrict__ g1, const float* __restrict__ be1,
                 const float* __restrict__ m1, const float* __restrict__ v1,
                 ushort_t* __restrict__ w_bf, float* __restrict__ o1g)
{
    const int t = blockIdx.x * 256 + threadIdx.x;
    if (t < 320 * 80) {
        const int u = t / 80, j = t - u * 80;
        float val = 0.f;
        if (u < U_ && j < 76) {
            const int tp = j >> 2;          // kernel position 0..18
            const int d  = j & 3;           // DNA channel 0..3
            const float s1 = g1[u] / sqrtf(v1[u] + EPS_);
            val = w_conv[u * 76 + 19 * d + tp] * s1;
        }
        const int nt = u >> 5, r = u & 31;
        const int kc = j >> 4, rem = j & 15;
        w_bf[nt * 2560 + kc * 512 + r * 16 + rem] = f2bf(val);
    }
    if (t < 320) {
        float o = 0.f;
        if (t < U_) {
            const float s1 = g1[t] / sqrtf(v1[t] + EPS_);
            o = (b_conv[t] - m1[t]) * s1 + be1[t];
        }
        o1g[t] = o;
    }
}

// ---------------------------------------------------------------------------
// conv_mfma_k: implicit-GEMM conv + BN1 + maxpool + exp, pooling IN REGISTERS.
// TWO batches per block: each wave runs two INDEPENDENT MFMA chains sharing
// the B-fragments -> MFMA latency hidden by ILP, B traffic per MFMA halved.
// 448 threads = 7 waves; wave wv = m-tile wv (4 windows). Grid 640 1-D,
// XCD-swizzled: the 5 bx blocks of a batch-pair share bid%8 -> same XCD L2
// (pooled row writes merge; x reuse).
// Staging: GEMM rows 0..199 read x4 rows l..l+18 -> 220 rows per batch.
// Per-tile row permutation puts two complete 7-row pool windows in each
// lane-half's C slots; window max = fmax over acc regs; one barrier.
// ---------------------------------------------------------------------------
__global__ __launch_bounds__(448, 4)
void conv_mfma_k(const float4* __restrict__ x4,        // (B,1000) float4 (D=4)
                 const ushort_t* __restrict__ w_bf,    // packed tiles (see pack)
                 const float* __restrict__ o1g,        // (320)
                 ushort_t* __restrict__ pooled)        // (U,B,P) bf16
{
    __shared__ ushort_t xls[2][880];     // bf16 x_flat rows l0..l0+219, 2 batches
    const int tid = threadIdx.x;
    // XCD-swizzle decode: bid = (pair%8) + 8*((pair/8)*5 + bx)
    const int bid = blockIdx.x;
    const int r8 = bid & 7, kk = bid >> 3;
    const int bx = kk % 5, p8 = kk / 5;
    const int pair = p8 * 8 + r8;        // 0..127
    const int b0 = 2 * pair;             // batches b0, b0+1
    const int w0 = bx * 28;              // first window of block
    const int l0 = w0 * 7;               // first conv row (bx*196, max 784)

    if (tid < 440) {
        const int which = (tid >= 220) ? 1 : 0;
        const int i = tid - 220 * which;
        const int gi = l0 + i;
        float4 v = make_float4(0.f, 0.f, 0.f, 0.f);
        if (gi < L_) v = x4[(size_t)(b0 + which) * L_ + gi];
        ushort4 pk4;
        pk4.x = f2bf(v.x); pk4.y = f2bf(v.y); pk4.z = f2bf(v.z); pk4.w = f2bf(v.w);
        *(ushort4*)&xls[which][4 * i] = pk4;
    }
    __syncthreads();

    const int lane = tid & 63;
    const int mt   = tid >> 6;           // m-tile 0..6
    const int half = lane >> 5;
    const int r32  = lane & 31;

    // permuted A-row offset for slot r32
    const int sreg = (r32 & 3) + 4 * (r32 >> 3);
    const int sh   = (r32 >> 2) & 1;
    const int off  = sreg < 7  ? sreg + 7 * sh
                   : sreg < 14 ? sreg + 7 + 7 * sh
                               : 28 + (sreg - 14) + 2 * sh;

    const char* xb0 = (const char*)&xls[0][0] + 8 * (28 * mt + off) + 16 * half;
    const char* xb1 = xb0 + 1760;        // xls[1] is 880 ushorts later
    const char* wbase = (const char*)w_bf + 32 * r32 + 16 * half;

    // hoist nt-invariant A-fragments (both batches) into registers
    short8v aA0[5], aA1[5];
#pragma unroll
    for (int kc = 0; kc < 5; ++kc) {
        aA0[kc] = *(const short8v*)(xb0 + 32 * kc);
        aA1[kc] = *(const short8v*)(xb1 + 32 * kc);
    }

    const int pA = w0 + 4 * mt;          // window base of this tile (<=136)

    for (int nt = 0; nt < 10; ++nt) {
        short8v bfr[5];
        const char* wn = wbase + nt * 5120;
#pragma unroll
        for (int kc = 0; kc < 5; ++kc)
            bfr[kc] = *(const short8v*)(wn + 1024 * kc);
        const float o1u = o1g[nt * 32 + r32];

        f32x16 acc0 = {};
        f32x16 acc1 = {};
#pragma unroll
        for (int kc = 0; kc < 5; ++kc) {
            acc0 = __builtin_amdgcn_mfma_f32_32x32x16_bf16(aA0[kc], bfr[kc], acc0, 0, 0, 0);
            acc1 = __builtin_amdgcn_mfma_f32_32x32x16_bf16(aA1[kc], bfr[kc], acc1, 0, 0, 0);
        }

        // in-register pooling for both batches (o1 added after max; exp monotone)
        float m00 = acc0[0], m01 = acc0[7];
        float m10 = acc1[0], m11 = acc1[7];
#pragma unroll
        for (int j = 1; j < 7; ++j)  { m00 = fmaxf(m00, acc0[j]); m10 = fmaxf(m10, acc1[j]); }
#pragma unroll
        for (int j = 8; j < 14; ++j) { m01 = fmaxf(m01, acc0[j]); m11 = fmaxf(m11, acc1[j]); }

        const unsigned pk0 = (unsigned)f2bf(__expf(m00 + o1u)) |
                             ((unsigned)f2bf(__expf(m01 + o1u)) << 16);
        const unsigned pk1 = (unsigned)f2bf(__expf(m10 + o1u)) |
                             ((unsigned)f2bf(__expf(m11 + o1u)) << 16);
        const unsigned ot0 = __shfl_xor(pk0, 32);
        const unsigned ot1 = __shfl_xor(pk1, 32);

        const int u = nt * 32 + r32;
        if (u < U_ && half == 0) {       // windows pA..pA+3 (pA+3 <= 139 always)
            ushort4 st0, st1;
            st0.x = (ushort_t)(pk0 & 0xffff);   // p+0 (own m0)
            st0.y = (ushort_t)(ot0 & 0xffff);   // p+1 (other m0)
            st0.z = (ushort_t)(pk0 >> 16);      // p+2 (own m1)
            st0.w = (ushort_t)(ot0 >> 16);      // p+3 (other m1)
            st1.x = (ushort_t)(pk1 & 0xffff);
            st1.y = (ushort_t)(ot1 & 0xffff);
            st1.z = (ushort_t)(pk1 >> 16);
            st1.w = (ushort_t)(ot1 >> 16);
            ushort_t* row = &pooled[((size_t)u * B_ + b0) * P_ + pA];
            *(ushort4*)row         = st0;
            *(ushort4*)(row + P_)  = st1;       // batch b0+1
        }
    }
}

// ---------------------------------------------------------------------------
// fc_mfma_k: per-unit FC1 via MFMA + BN2+ReLU+FC2+BN3+ReLU -> zT (B,304)
// 1-D grid 600, XCD-swizzled so both bt blocks of a unit share an XCD L2
// (w_fc1 panel fetched from HBM once). 4 waves = 4 m-tiles x all 4 n-tiles.
// B-operand: raw w_fc1 f32 panel staged into LDS as bf16 (unscaled); BN2
// scale applied in the f32 epilogue.
// ---------------------------------------------------------------------------
__global__ __launch_bounds__(256, 3)
void fc_mfma_k(const ushort_t* __restrict__ pooled,  // (U,B,P) bf16
               const float* __restrict__ w_fc1,      // (U,FC,P) f32
               const float* __restrict__ b_fc1,
               const float* __restrict__ g2,
               const float* __restrict__ be2,
               const float* __restrict__ m2,
               const float* __restrict__ v2,
               const float* __restrict__ w_fc2,
               const float* __restrict__ b_fc2,
               const float* __restrict__ g3,
               const float* __restrict__ be3,
               const float* __restrict__ m3,
               const float* __restrict__ v3,
               float* __restrict__ zT)               // (B,304)
{
    __shared__ ushort_t wlds[FC_ * WLD_];  // 100 rows x 144 bf16 = 28.8 KB
    __shared__ float zred[128][33];
    const int tid  = threadIdx.x;
    // XCD-swizzle decode: u<296: bid = (u%8) + 8*((u/8)*2 + bt); tail appended
    const int bid = blockIdx.x;
    int u, bt;
    if (bid < 592) {
        const int r = bid & 7, k = bid >> 3;
        bt = k & 1;
        u  = (k >> 1) * 8 + r;
    } else {
        const int t = bid - 592;
        u  = 296 + (t >> 1);
        bt = t & 1;
    }

    // stage raw w_fc1 panel -> bf16 LDS (coalesced float4 reads)
    const float* __restrict__ wsrc = w_fc1 + (size_t)u * FC_ * P_;
    for (int idx = tid; idx < FC_ * 35; idx += 256) {
        const int f = idx / 35, j = idx - f * 35;
        const float4 v = *(const float4*)(wsrc + f * P_ + 4 * j);
        ushort4 pk;
        pk.x = f2bf(v.x); pk.y = f2bf(v.y); pk.z = f2bf(v.z); pk.w = f2bf(v.w);
        *(ushort4*)&wlds[f * WLD_ + 4 * j] = pk;
    }
    for (int idx = tid; idx < FC_ * 4; idx += 256) {
        const int f = idx >> 2, k = 140 + (idx & 3);
        wlds[f * WLD_ + k] = 0;
    }
    __syncthreads();

    const int lane = tid & 63;
    const int wv   = tid >> 6;            // m-tile within the 128-batch panel
    const int half = lane >> 5;
    const int r32  = lane & 31;

    const int brow = bt * 128 + wv * 32 + r32;
    const ushort_t* __restrict__ abase =
        pooled + ((size_t)u * B_ + brow) * P_ + half * 8;

    const ushort_t* __restrict__ bl0 = &wlds[r32 * WLD_ + half * 8];
    const ushort_t* __restrict__ bl1 = &wlds[(32 + r32) * WLD_ + half * 8];
    const ushort_t* __restrict__ bl2 = &wlds[(64 + r32) * WLD_ + half * 8];
    const int f3c = (96 + r32 < FC_) ? (96 + r32) : (FC_ - 1);   // clamp
    const ushort_t* __restrict__ bl3 = &wlds[f3c * WLD_ + half * 8];

    // A software-pipelined; B from LDS (low latency)
    short8v ac = *(const short8v*)(abase);
    f32x16 acc0 = {}, acc1 = {}, acc2 = {}, acc3 = {};
#pragma unroll
    for (int kc = 0; kc < 9; ++kc) {
        const int kn = (kc < 8) ? kc + 1 : kc;
        const short8v an = *(const short8v*)(abase + kn * 16);
        const short8v b0 = *(const short8v*)(bl0 + kc * 16);
        const short8v b1 = *(const short8v*)(bl1 + kc * 16);
        const short8v b2 = *(const short8v*)(bl2 + kc * 16);
        const short8v b3 = *(const short8v*)(bl3 + kc * 16);
        acc0 = __builtin_amdgcn_mfma_f32_32x32x16_bf16(ac, b0, acc0, 0, 0, 0);
        acc1 = __builtin_amdgcn_mfma_f32_32x32x16_bf16(ac, b1, acc1, 0, 0, 0);
        acc2 = __builtin_amdgcn_mfma_f32_32x32x16_bf16(ac, b2, acc2, 0, 0, 0);
        acc3 = __builtin_amdgcn_mfma_f32_32x32x16_bf16(ac, b3, acc3, 0, 0, 0);
        ac = an;
    }

    // inline BN2 params per lane (4 f-columns)
    float s2[4], o2[4], w2[4];
#pragma unroll
    for (int n = 0; n < 4; ++n) {
        const int f = n * 32 + r32;
        if (f < FC_) {
            const int fg = u * FC_ + f;
            const float ss = g2[fg] / sqrtf(v2[fg] + EPS_);
            s2[n] = ss;
            o2[n] = (b_fc1[fg] - m2[fg]) * ss + be2[fg];
            w2[n] = w_fc2[fg];
        } else {
            s2[n] = 0.f; o2[n] = 0.f; w2[n] = 0.f;
        }
    }
#pragma unroll
    for (int rg = 0; rg < 16; ++rg) {
        const int row = (rg & 3) + 8 * (rg >> 2) + 4 * half;
        float s = fmaxf(fmaf(acc0[rg], s2[0], o2[0]), 0.f) * w2[0];
        s = fmaf(fmaxf(fmaf(acc1[rg], s2[1], o2[1]), 0.f), w2[1], s);
        s = fmaf(fmaxf(fmaf(acc2[rg], s2[2], o2[2]), 0.f), w2[2], s);
        s = fmaf(fmaxf(fmaf(acc3[rg], s2[3], o2[3]), 0.f), w2[3], s);
        zred[wv * 32 + row][r32] = s;
    }
    __syncthreads();

    // reduce 32 lane-partials per batch row; write transposed (B,304)
    if (tid < 128) {
        float s = 0.f;
#pragma unroll
        for (int j = 0; j < 32; ++j) s += zred[tid][j];
        const float s3 = g3[u] / sqrtf(v3[u] + EPS_);
        const float o3 = (b_fc2[u] - m3[u]) * s3 + be3[u];
        zT[(size_t)(bt * 128 + tid) * 304 + u] = fmaxf(fmaf(s, s3, o3), 0.f);
    }
}

// ---------------------------------------------------------------------------
// out_k: out[b] = sigmoid( dot(zT[b,0:300], w_out) + b_out ), coalesced f4.
// ---------------------------------------------------------------------------
__global__ __launch_bounds__(64, 8)
void out_k(const float* __restrict__ zT,      // (B,304)
           const float* __restrict__ w_out,   // (U,1)
           const float* __restrict__ b_out,   // (1,)
           float* __restrict__ out)           // (B,1)
{
    const int lane = threadIdx.x;
    const int b    = blockIdx.x;
    const float4* zr = (const float4*)(zT + (size_t)b * 304);
    const float4* w4 = (const float4*)w_out;

    float s = 0.f;
    for (int i = lane; i < 75; i += 64) {
        const float4 z = zr[i], w = w4[i];
        s += z.x * w.x + z.y * w.y + z.z * w.z + z.w * w.w;
    }
#pragma unroll
    for (int o = 32; o > 0; o >>= 1) s += __shfl_xor(s, o);
    if (lane == 0)
        out[b] = 1.0f / (1.0f + __expf(-(s + b_out[0])));
}

// ---------------------------------------------------------------------------
extern "C" void kernel_launch(void* const* d_in, const int* in_sizes, int n_in,
                              void* d_out, int out_size, void* d_ws, size_t ws_size,
                              hipStream_t stream)
{
    const float* input_seq = (const float*)d_in[0];   // (B,L,4)
    const float* w_conv    = (const float*)d_in[1];
    const float* b_conv    = (const float*)d_in[2];
    const float* g1        = (const float*)d_in[3];
    const float* be1       = (const float*)d_in[4];
    const float* m1        = (const float*)d_in[5];
    const float* v1        = (const float*)d_in[6];
    const float* w_fc1     = (const float*)d_in[7];
    const float* b_fc1     = (const float*)d_in[8];
    const float* g2        = (const float*)d_in[9];
    const float* be2       = (const float*)d_in[10];
    const float* m2        = (const float*)d_in[11];
    const float* v2        = (const float*)d_in[12];
    const float* w_fc2     = (const float*)d_in[13];
    const float* b_fc2     = (const float*)d_in[14];
    const float* g3        = (const float*)d_in[15];
    const float* be3       = (const float*)d_in[16];
    const float* m3        = (const float*)d_in[17];
    const float* v3        = (const float*)d_in[18];
    const float* w_out     = (const float*)d_in[19];
    const float* b_out     = (const float*)d_in[20];

    // Workspace layout (~21.9 MB of ws):
    char* p = (char*)d_ws;
    ushort_t* pooled = (ushort_t*)p;   p += (size_t)B_ * U_ * P_ * 2;   // 21,504,000
    ushort_t* w_bf   = (ushort_t*)p;   p += 320 * 80 * 2;               //     51,200
    float*    o1g    = (float*)p;      p += 320 * 4;                    //      1,280
    float*    zT     = (float*)p;      p += (size_t)B_ * 304 * 4;       //    311,296

    pack_conv_k<<<dim3(100), 256, 0, stream>>>(
        w_conv, b_conv, g1, be1, m1, v1, w_bf, o1g);

    conv_mfma_k<<<dim3(640), 448, 0, stream>>>(
        (const float4*)input_seq, w_bf, o1g, pooled);

    fc_mfma_k<<<dim3(600), 256, 0, stream>>>(
        pooled, w_fc1, b_fc1, g2, be2, m2, v2, w_fc2, b_fc2,
        g3, be3, m3, v3, zT);

    out_k<<<dim3(B_), 64, 0, stream>>>(zT, w_out, b_out, (float*)d_out);
}

// Round 14
// 60.701 us; speedup vs baseline: 1.0674x; 1.0674x over previous
//
#include <hip/hip_runtime.h>
#include <hip/hip_bf16.h>
#include <math.h>

// Problem constants
#define U_   300
#define K_   19
#define FC_  100
#define B_   256
#define L_   1000
#define P_   140     // pooled length
#define EPS_ 1e-5f
#define WLD_ 144     // fc LDS row stride (bf16): 288 B, 16-B aligned

typedef unsigned short ushort_t;
typedef __attribute__((ext_vector_type(8)))  short short8v;   // 8 bf16 = 4 VGPR
typedef __attribute__((ext_vector_type(16))) float f32x16;    // MFMA 32x32 acc

// f32 -> bf16 round-to-nearest-even (bit trick)
__device__ __forceinline__ ushort_t f2bf(float f) {
    union { float f; unsigned u; } a; a.f = f;
    unsigned r = a.u + 0x7fffu + ((a.u >> 16) & 1u);
    return (ushort_t)(r >> 16);
}

// ---------------------------------------------------------------------------
// pack_conv_k: conv weights -> bf16, BN1 scale folded, COALESCED-TILE layout:
//   element offset = nt*2560 + kc*512 + r*16 + half*8 + e
// (u = nt*32 + r, GEMM-k j = kc*16 + half*8 + e, j order = 4*t + d).
// A wave's B-frag load (fixed kc) is 64 lanes x 16 B contiguous = 2 KB.
// ---------------------------------------------------------------------------
__global__ __launch_bounds__(256, 4)
void pack_conv_k(const float* __restrict__ w_conv, const float* __restrict__ b_conv,
                 const float* __restrict__ g1, const float* __restrict__ be1,
                 const float* __restrict__ m1, const float* __restrict__ v1,
                 ushort_t* __restrict__ w_bf, float* __restrict__ o1g)
{
    const int t = blockIdx.x * 256 + threadIdx.x;
    if (t < 320 * 80) {
        const int u = t / 80, j = t - u * 80;
        float val = 0.f;
        if (u < U_ && j < 76) {
            const int tp = j >> 2;          // kernel position 0..18
            const int d  = j & 3;           // DNA channel 0..3
            const float s1 = g1[u] / sqrtf(v1[u] + EPS_);
            val = w_conv[u * 76 + 19 * d + tp] * s1;
        }
        const int nt = u >> 5, r = u & 31;
        const int kc = j >> 4, rem = j & 15;
        w_bf[nt * 2560 + kc * 512 + r * 16 + rem] = f2bf(val);
    }
    if (t < 320) {
        float o = 0.f;
        if (t < U_) {
            const float s1 = g1[t] / sqrtf(v1[t] + EPS_);
            o = (b_conv[t] - m1[t]) * s1 + be1[t];
        }
        o1g[t] = o;
    }
}

// ---------------------------------------------------------------------------
// conv_mfma_k: implicit-GEMM conv + BN1 + maxpool + exp.
// Two batches per block (independent MFMA chains share B-frags -> ILP).
// 448 threads = 7 waves = 7 m-tiles (4 windows each; 5 bx x 28 = 140 exact).
// In-register pooling via per-tile row permutation (two 7-row windows per
// lane-half's C slots). NEW: results funneled through a small LDS stage and
// drained with COALESCED ushort4 stores (7 lanes = 56 contiguous B per row)
// -- the old direct store hit 32 distinct lines per instr (TA-bound, ~37us).
// ---------------------------------------------------------------------------
__global__ __launch_bounds__(448, 4)
void conv_mfma_k(const float4* __restrict__ x4,        // (B,1000) float4 (D=4)
                 const ushort_t* __restrict__ w_bf,    // packed tiles (see pack)
                 const float* __restrict__ o1g,        // (320)
                 ushort_t* __restrict__ pooled)        // (U,B,P) bf16
{
    __shared__ ushort_t xls[2][880];     // bf16 x_flat rows l0..l0+219, 2 batches
    __shared__ ushort_t stage[32][68];   // [u-local][b*32 + p-local], 136 B/row
    const int tid = threadIdx.x;
    const int bx  = blockIdx.x;          // 0..4
    const int b0  = 2 * blockIdx.y;      // batches b0, b0+1
    const int w0  = bx * 28;             // first window of block
    const int l0  = w0 * 7;              // first conv row (bx*196, max 784)

    if (tid < 440) {
        const int which = (tid >= 220) ? 1 : 0;
        const int i = tid - 220 * which;
        const int gi = l0 + i;
        float4 v = make_float4(0.f, 0.f, 0.f, 0.f);
        if (gi < L_) v = x4[(size_t)(b0 + which) * L_ + gi];
        ushort4 pk4;
        pk4.x = f2bf(v.x); pk4.y = f2bf(v.y); pk4.z = f2bf(v.z); pk4.w = f2bf(v.w);
        *(ushort4*)&xls[which][4 * i] = pk4;
    }
    __syncthreads();

    const int lane = tid & 63;
    const int mt   = tid >> 6;           // m-tile 0..6
    const int half = lane >> 5;
    const int r32  = lane & 31;

    // permuted A-row offset for slot r32
    const int sreg = (r32 & 3) + 4 * (r32 >> 3);
    const int sh   = (r32 >> 2) & 1;
    const int off  = sreg < 7  ? sreg + 7 * sh
                   : sreg < 14 ? sreg + 7 + 7 * sh
                               : 28 + (sreg - 14) + 2 * sh;

    const char* xb0 = (const char*)&xls[0][0] + 8 * (28 * mt + off) + 16 * half;
    const char* xb1 = xb0 + 1760;        // xls[1] is 880 ushorts later
    const char* wbase = (const char*)w_bf + 32 * r32 + 16 * half;

    // hoist nt-invariant A-fragments (both batches) into registers
    short8v aA0[5], aA1[5];
#pragma unroll
    for (int kc = 0; kc < 5; ++kc) {
        aA0[kc] = *(const short8v*)(xb0 + 32 * kc);
        aA1[kc] = *(const short8v*)(xb1 + 32 * kc);
    }

    // drain mapping: thread -> (u-local, b-local, 4-window chunk)
    const int dr  = tid / 7;             // 0..63
    const int dcc = tid - 7 * dr;        // 0..6
    const int dul = dr >> 1;             // u-local 0..31
    const int dbl = dr & 1;              // batch-local

    // stage indices this lane writes: poff = 4*mt + {half, 2+half}
    const int p0off = 4 * mt + half;

    for (int nt = 0; nt < 10; ++nt) {
        short8v bfr[5];
        const char* wn = wbase + nt * 5120;
#pragma unroll
        for (int kc = 0; kc < 5; ++kc)
            bfr[kc] = *(const short8v*)(wn + 1024 * kc);
        const float o1u = o1g[nt * 32 + r32];

        f32x16 acc0 = {};
        f32x16 acc1 = {};
#pragma unroll
        for (int kc = 0; kc < 5; ++kc) {
            acc0 = __builtin_amdgcn_mfma_f32_32x32x16_bf16(aA0[kc], bfr[kc], acc0, 0, 0, 0);
            acc1 = __builtin_amdgcn_mfma_f32_32x32x16_bf16(aA1[kc], bfr[kc], acc1, 0, 0, 0);
        }

        // in-register pooling for both batches (o1 added after max; exp monotone)
        float m00 = acc0[0], m01 = acc0[7];
        float m10 = acc1[0], m11 = acc1[7];
#pragma unroll
        for (int j = 1; j < 7; ++j)  { m00 = fmaxf(m00, acc0[j]); m10 = fmaxf(m10, acc1[j]); }
#pragma unroll
        for (int j = 8; j < 14; ++j) { m01 = fmaxf(m01, acc0[j]); m11 = fmaxf(m11, acc1[j]); }

        // LDS stage (bank: word = 34*r32 + 16*b + poff/2 -> 2-way, free)
        stage[r32][p0off]          = f2bf(__expf(m00 + o1u));   // b0, window 4mt+half
        stage[r32][p0off + 2]      = f2bf(__expf(m01 + o1u));   // b0, window 4mt+2+half
        stage[r32][32 + p0off]     = f2bf(__expf(m10 + o1u));   // b1
        stage[r32][32 + p0off + 2] = f2bf(__expf(m11 + o1u));
        __syncthreads();

        // coalesced drain: 448 threads = 64 rows x 7 ushort4 chunks
        const int ug = nt * 32 + dul;
        if (ug < U_) {
            const ushort4 st = *(const ushort4*)&stage[dul][dbl * 32 + 4 * dcc];
            *(ushort4*)&pooled[((size_t)ug * B_ + (b0 + dbl)) * P_ + w0 + 4 * dcc] = st;
        }
        __syncthreads();   // stage reused next nt
    }
}

// ---------------------------------------------------------------------------
// fc_mfma_k: per-unit FC1 via MFMA + BN2+ReLU+FC2+BN3+ReLU -> zT (B,304)
// 1-D grid 600, XCD-swizzled so both bt blocks of a unit share an XCD L2.
// 4 waves = 4 m-tiles x all 4 n-tiles. B: raw w_fc1 staged to LDS as bf16
// (unscaled); BN2 scale applied in f32 epilogue.
// ---------------------------------------------------------------------------
__global__ __launch_bounds__(256, 3)
void fc_mfma_k(const ushort_t* __restrict__ pooled,  // (U,B,P) bf16
               const float* __restrict__ w_fc1,      // (U,FC,P) f32
               const float* __restrict__ b_fc1,
               const float* __restrict__ g2,
               const float* __restrict__ be2,
               const float* __restrict__ m2,
               const float* __restrict__ v2,
               const float* __restrict__ w_fc2,
               const float* __restrict__ b_fc2,
               const float* __restrict__ g3,
               const float* __restrict__ be3,
               const float* __restrict__ m3,
               const float* __restrict__ v3,
               float* __restrict__ zT)               // (B,304)
{
    __shared__ ushort_t wlds[FC_ * WLD_];  // 100 rows x 144 bf16 = 28.8 KB
    __shared__ float zred[128][33];
    const int tid  = threadIdx.x;
    // XCD-swizzle decode: u<296: bid = (u%8) + 8*((u/8)*2 + bt); tail appended
    const int bid = blockIdx.x;
    int u, bt;
    if (bid < 592) {
        const int r = bid & 7, k = bid >> 3;
        bt = k & 1;
        u  = (k >> 1) * 8 + r;
    } else {
        const int t = bid - 592;
        u  = 296 + (t >> 1);
        bt = t & 1;
    }

    // stage raw w_fc1 panel -> bf16 LDS (coalesced float4 reads)
    const float* __restrict__ wsrc = w_fc1 + (size_t)u * FC_ * P_;
    for (int idx = tid; idx < FC_ * 35; idx += 256) {
        const int f = idx / 35, j = idx - f * 35;
        const float4 v = *(const float4*)(wsrc + f * P_ + 4 * j);
        ushort4 pk;
        pk.x = f2bf(v.x); pk.y = f2bf(v.y); pk.z = f2bf(v.z); pk.w = f2bf(v.w);
        *(ushort4*)&wlds[f * WLD_ + 4 * j] = pk;
    }
    for (int idx = tid; idx < FC_ * 4; idx += 256) {
        const int f = idx >> 2, k = 140 + (idx & 3);
        wlds[f * WLD_ + k] = 0;
    }
    __syncthreads();

    const int lane = tid & 63;
    const int wv   = tid >> 6;            // m-tile within the 128-batch panel
    const int half = lane >> 5;
    const int r32  = lane & 31;

    const int brow = bt * 128 + wv * 32 + r32;
    const ushort_t* __restrict__ abase =
        pooled + ((size_t)u * B_ + brow) * P_ + half * 8;

    const ushort_t* __restrict__ bl0 = &wlds[r32 * WLD_ + half * 8];
    const ushort_t* __restrict__ bl1 = &wlds[(32 + r32) * WLD_ + half * 8];
    const ushort_t* __restrict__ bl2 = &wlds[(64 + r32) * WLD_ + half * 8];
    const int f3c = (96 + r32 < FC_) ? (96 + r32) : (FC_ - 1);   // clamp
    const ushort_t* __restrict__ bl3 = &wlds[f3c * WLD_ + half * 8];

    // A software-pipelined; B from LDS (low latency)
    short8v ac = *(const short8v*)(abase);
    f32x16 acc0 = {}, acc1 = {}, acc2 = {}, acc3 = {};
#pragma unroll
    for (int kc = 0; kc < 9; ++kc) {
        const int kn = (kc < 8) ? kc + 1 : kc;
        const short8v an = *(const short8v*)(abase + kn * 16);
        const short8v b0 = *(const short8v*)(bl0 + kc * 16);
        const short8v b1 = *(const short8v*)(bl1 + kc * 16);
        const short8v b2 = *(const short8v*)(bl2 + kc * 16);
        const short8v b3 = *(const short8v*)(bl3 + kc * 16);
        acc0 = __builtin_amdgcn_mfma_f32_32x32x16_bf16(ac, b0, acc0, 0, 0, 0);
        acc1 = __builtin_amdgcn_mfma_f32_32x32x16_bf16(ac, b1, acc1, 0, 0, 0);
        acc2 = __builtin_amdgcn_mfma_f32_32x32x16_bf16(ac, b2, acc2, 0, 0, 0);
        acc3 = __builtin_amdgcn_mfma_f32_32x32x16_bf16(ac, b3, acc3, 0, 0, 0);
        ac = an;
    }

    // inline BN2 params per lane (4 f-columns)
    float s2[4], o2[4], w2[4];
#pragma unroll
    for (int n = 0; n < 4; ++n) {
        const int f = n * 32 + r32;
        if (f < FC_) {
            const int fg = u * FC_ + f;
            const float ss = g2[fg] / sqrtf(v2[fg] + EPS_);
            s2[n] = ss;
            o2[n] = (b_fc1[fg] - m2[fg]) * ss + be2[fg];
            w2[n] = w_fc2[fg];
        } else {
            s2[n] = 0.f; o2[n] = 0.f; w2[n] = 0.f;
        }
    }
#pragma unroll
    for (int rg = 0; rg < 16; ++rg) {
        const int row = (rg & 3) + 8 * (rg >> 2) + 4 * half;
        float s = fmaxf(fmaf(acc0[rg], s2[0], o2[0]), 0.f) * w2[0];
        s = fmaf(fmaxf(fmaf(acc1[rg], s2[1], o2[1]), 0.f), w2[1], s);
        s = fmaf(fmaxf(fmaf(acc2[rg], s2[2], o2[2]), 0.f), w2[2], s);
        s = fmaf(fmaxf(fmaf(acc3[rg], s2[3], o2[3]), 0.f), w2[3], s);
        zred[wv * 32 + row][r32] = s;
    }
    __syncthreads();

    // reduce 32 lane-partials per batch row; write transposed (B,304)
    if (tid < 128) {
        float s = 0.f;
#pragma unroll
        for (int j = 0; j < 32; ++j) s += zred[tid][j];
        const float s3 = g3[u] / sqrtf(v3[u] + EPS_);
        const float o3 = (b_fc2[u] - m3[u]) * s3 + be3[u];
        zT[(size_t)(bt * 128 + tid) * 304 + u] = fmaxf(fmaf(s, s3, o3), 0.f);
    }
}

// ---------------------------------------------------------------------------
// out_k: out[b] = sigmoid( dot(zT[b,0:300], w_out) + b_out ), coalesced f4.
// ---------------------------------------------------------------------------
__global__ __launch_bounds__(64, 8)
void out_k(const float* __restrict__ zT,      // (B,304)
           const float* __restrict__ w_out,   // (U,1)
           const float* __restrict__ b_out,   // (1,)
           float* __restrict__ out)           // (B,1)
{
    const int lane = threadIdx.x;
    const int b    = blockIdx.x;
    const float4* zr = (const float4*)(zT + (size_t)b * 304);
    const float4* w4 = (const float4*)w_out;

    float s = 0.f;
    for (int i = lane; i < 75; i += 64) {
        const float4 z = zr[i], w = w4[i];
        s += z.x * w.x + z.y * w.y + z.z * w.z + z.w * w.w;
    }
#pragma unroll
    for (int o = 32; o > 0; o >>= 1) s += __shfl_xor(s, o);
    if (lane == 0)
        out[b] = 1.0f / (1.0f + __expf(-(s + b_out[0])));
}

// ---------------------------------------------------------------------------
extern "C" void kernel_launch(void* const* d_in, const int* in_sizes, int n_in,
                              void* d_out, int out_size, void* d_ws, size_t ws_size,
                              hipStream_t stream)
{
    const float* input_seq = (const float*)d_in[0];   // (B,L,4)
    const float* w_conv    = (const float*)d_in[1];
    const float* b_conv    = (const float*)d_in[2];
    const float* g1        = (const float*)d_in[3];
    const float* be1       = (const float*)d_in[4];
    const float* m1        = (const float*)d_in[5];
    const float* v1        = (const float*)d_in[6];
    const float* w_fc1     = (const float*)d_in[7];
    const float* b_fc1     = (const float*)d_in[8];
    const float* g2        = (const float*)d_in[9];
    const float* be2       = (const float*)d_in[10];
    const float* m2        = (const float*)d_in[11];
    const float* v2        = (const float*)d_in[12];
    const float* w_fc2     = (const float*)d_in[13];
    const float* b_fc2     = (const float*)d_in[14];
    const float* g3        = (const float*)d_in[15];
    const float* be3       = (const float*)d_in[16];
    const float* m3        = (const float*)d_in[17];
    const float* v3        = (const float*)d_in[18];
    const float* w_out     = (const float*)d_in[19];
    const float* b_out     = (const float*)d_in[20];

    // Workspace layout (~21.9 MB of ws):
    char* p = (char*)d_ws;
    ushort_t* pooled = (ushort_t*)p;   p += (size_t)B_ * U_ * P_ * 2;   // 21,504,000
    ushort_t* w_bf   = (ushort_t*)p;   p += 320 * 80 * 2;               //     51,200
    float*    o1g    = (float*)p;      p += 320 * 4;                    //      1,280
    float*    zT     = (float*)p;      p += (size_t)B_ * 304 * 4;       //    311,296

    pack_conv_k<<<dim3(100), 256, 0, stream>>>(
        w_conv, b_conv, g1, be1, m1, v1, w_bf, o1g);

    conv_mfma_k<<<dim3(5, 128), 448, 0, stream>>>(
        (const float4*)input_seq, w_bf, o1g, pooled);

    fc_mfma_k<<<dim3(600), 256, 0, stream>>>(
        pooled, w_fc1, b_fc1, g2, be2, m2, v2, w_fc2, b_fc2,
        g3, be3, m3, v3, zT);

    out_k<<<dim3(B_), 64, 0, stream>>>(zT, w_out, b_out, (float*)d_out);
}

// Round 15
// 55.782 us; speedup vs baseline: 1.1616x; 1.0882x over previous
//
#include <hip/hip_runtime.h>
#include <hip/hip_bf16.h>
#include <math.h>

// Problem constants
#define U_   300
#define K_   19
#define FC_  100
#define B_   256
#define L_   1000
#define P_   140     // pooled length
#define EPS_ 1e-5f
#define WLD_ 144     // fc LDS row stride (bf16): 288 B, 16-B aligned

typedef unsigned short ushort_t;
typedef __attribute__((ext_vector_type(8)))  short short8v;   // 8 bf16 = 4 VGPR
typedef __attribute__((ext_vector_type(16))) float f32x16;    // MFMA 32x32 acc

// f32 -> bf16 round-to-nearest-even (bit trick)
__device__ __forceinline__ ushort_t f2bf(float f) {
    union { float f; unsigned u; } a; a.f = f;
    unsigned r = a.u + 0x7fffu + ((a.u >> 16) & 1u);
    return (ushort_t)(r >> 16);
}

// ---------------------------------------------------------------------------
// pack_conv_k: conv weights -> bf16, BN1 scale folded, LANE-LINEAR tile layout:
//   element offset = nt*2560 + kc*512 + half*256 + r*8 + e
// (u = nt*32 + r, GEMM-k j = kc*16 + half*8 + e, j order = 4*t + d).
// MFMA lane (half*32+r) then reads its 16 B at byte offset lane*16 within the
// (nt,kc) 1-KB slab -> linear ds_read_b128, conflict-free.
// ---------------------------------------------------------------------------
__global__ __launch_bounds__(256, 4)
void pack_conv_k(const float* __restrict__ w_conv, const float* __restrict__ b_conv,
                 const float* __restrict__ g1, const float* __restrict__ be1,
                 const float* __restrict__ m1, const float* __restrict__ v1,
                 ushort_t* __restrict__ w_bf, float* __restrict__ o1g)
{
    const int t = blockIdx.x * 256 + threadIdx.x;
    if (t < 320 * 80) {
        const int u = t / 80, j = t - u * 80;
        float val = 0.f;
        if (u < U_ && j < 76) {
            const int tp = j >> 2;          // kernel position 0..18
            const int d  = j & 3;           // DNA channel 0..3
            const float s1 = g1[u] / sqrtf(v1[u] + EPS_);
            val = w_conv[u * 76 + 19 * d + tp] * s1;
        }
        const int nt = u >> 5, r = u & 31;
        const int kc = j >> 4, rem = j & 15;
        const int half = rem >> 3, e = rem & 7;
        w_bf[nt * 2560 + kc * 512 + half * 256 + r * 8 + e] = f2bf(val);
    }
    if (t < 320) {
        float o = 0.f;
        if (t < U_) {
            const float s1 = g1[t] / sqrtf(v1[t] + EPS_);
            o = (b_conv[t] - m1[t]) * s1 + be1[t];
        }
        o1g[t] = o;
    }
}

// ---------------------------------------------------------------------------
// conv_mfma_k: implicit-GEMM conv + BN1 + maxpool + exp.
// KEY CHANGE: the whole packed weight table (51.2 KB) + o1 (1.3 KB) are
// staged into LDS once per block. Previously every wave re-read B-frags from
// L2 every nt (224 MB/dispatch out of a 51-KB footprint -> L2-channel
// hotspot; the invariant ~40us wall across 7 kernel variants). B-frag reads
// are now linear ds_read_b128 from LDS.
// Two batches per block (independent MFMA chains share B-frags -> ILP).
// 448 threads = 7 waves = 7 m-tiles (4 windows each; 5 bx x 28 = 140 exact).
// In-register pooling via per-tile row permutation; coalesced LDS-staged
// drain (round 14).
// ---------------------------------------------------------------------------
__global__ __launch_bounds__(448, 4)
void conv_mfma_k(const float4* __restrict__ x4,        // (B,1000) float4 (D=4)
                 const ushort_t* __restrict__ w_bf,    // packed tiles (see pack)
                 const float* __restrict__ o1g,        // (320)
                 ushort_t* __restrict__ pooled)        // (U,B,P) bf16
{
    __shared__ ushort_t xls[2][880];     // bf16 x_flat rows l0..l0+219, 2 batches
    __shared__ ushort_t wlds[25600];     // full packed weight table, 51.2 KB
    __shared__ float    o1l[320];
    __shared__ ushort_t stage[32][68];   // [u-local][b*32 + p-local], 136 B/row
    const int tid = threadIdx.x;
    const int bx  = blockIdx.x;          // 0..4
    const int b0  = 2 * blockIdx.y;      // batches b0, b0+1
    const int w0  = bx * 28;             // first window of block
    const int l0  = w0 * 7;              // first conv row (bx*196, max 784)

    // stage x rows (both batches) as bf16
    if (tid < 440) {
        const int which = (tid >= 220) ? 1 : 0;
        const int i = tid - 220 * which;
        const int gi = l0 + i;
        float4 v = make_float4(0.f, 0.f, 0.f, 0.f);
        if (gi < L_) v = x4[(size_t)(b0 + which) * L_ + gi];
        ushort4 pk4;
        pk4.x = f2bf(v.x); pk4.y = f2bf(v.y); pk4.z = f2bf(v.z); pk4.w = f2bf(v.w);
        *(ushort4*)&xls[which][4 * i] = pk4;
    }
    // stage full weight table + o1 into LDS (coalesced 16-B chunks)
    {
        const float4* ws = (const float4*)w_bf;
        float4* wd = (float4*)wlds;
        for (int i = tid; i < 3200; i += 448) wd[i] = ws[i];
        if (tid < 320) o1l[tid] = o1g[tid];
    }
    __syncthreads();

    const int lane = tid & 63;
    const int mt   = tid >> 6;           // m-tile 0..6
    const int half = lane >> 5;
    const int r32  = lane & 31;

    // permuted A-row offset for slot r32
    const int sreg = (r32 & 3) + 4 * (r32 >> 3);
    const int sh   = (r32 >> 2) & 1;
    const int off  = sreg < 7  ? sreg + 7 * sh
                   : sreg < 14 ? sreg + 7 + 7 * sh
                               : 28 + (sreg - 14) + 2 * sh;

    const char* xb0 = (const char*)&xls[0][0] + 8 * (28 * mt + off) + 16 * half;
    const char* xb1 = xb0 + 1760;        // xls[1] is 880 ushorts later
    const char* wl  = (const char*)wlds + 16 * lane;   // lane-linear B base

    // hoist nt-invariant A-fragments (both batches) into registers
    short8v aA0[5], aA1[5];
#pragma unroll
    for (int kc = 0; kc < 5; ++kc) {
        aA0[kc] = *(const short8v*)(xb0 + 32 * kc);
        aA1[kc] = *(const short8v*)(xb1 + 32 * kc);
    }

    // drain mapping: thread -> (u-local, b-local, 4-window chunk)
    const int dr  = tid / 7;             // 0..63
    const int dcc = tid - 7 * dr;        // 0..6
    const int dul = dr >> 1;             // u-local 0..31
    const int dbl = dr & 1;              // batch-local

    // stage indices this lane writes: poff = 4*mt + {half, 2+half}
    const int p0off = 4 * mt + half;

    for (int nt = 0; nt < 10; ++nt) {
        short8v bfr[5];
#pragma unroll
        for (int kc = 0; kc < 5; ++kc)
            bfr[kc] = *(const short8v*)(wl + nt * 5120 + kc * 1024);
        const float o1u = o1l[nt * 32 + r32];

        f32x16 acc0 = {};
        f32x16 acc1 = {};
#pragma unroll
        for (int kc = 0; kc < 5; ++kc) {
            acc0 = __builtin_amdgcn_mfma_f32_32x32x16_bf16(aA0[kc], bfr[kc], acc0, 0, 0, 0);
            acc1 = __builtin_amdgcn_mfma_f32_32x32x16_bf16(aA1[kc], bfr[kc], acc1, 0, 0, 0);
        }

        // in-register pooling for both batches (o1 added after max; exp monotone)
        float m00 = acc0[0], m01 = acc0[7];
        float m10 = acc1[0], m11 = acc1[7];
#pragma unroll
        for (int j = 1; j < 7; ++j)  { m00 = fmaxf(m00, acc0[j]); m10 = fmaxf(m10, acc1[j]); }
#pragma unroll
        for (int j = 8; j < 14; ++j) { m01 = fmaxf(m01, acc0[j]); m11 = fmaxf(m11, acc1[j]); }

        // LDS stage (2-way bank aliasing, free)
        stage[r32][p0off]          = f2bf(__expf(m00 + o1u));   // b0, window 4mt+half
        stage[r32][p0off + 2]      = f2bf(__expf(m01 + o1u));   // b0, window 4mt+2+half
        stage[r32][32 + p0off]     = f2bf(__expf(m10 + o1u));   // b1
        stage[r32][32 + p0off + 2] = f2bf(__expf(m11 + o1u));
        __syncthreads();

        // coalesced drain: 448 threads = 64 rows x 7 ushort4 chunks
        const int ug = nt * 32 + dul;
        if (ug < U_) {
            const ushort4 st = *(const ushort4*)&stage[dul][dbl * 32 + 4 * dcc];
            *(ushort4*)&pooled[((size_t)ug * B_ + (b0 + dbl)) * P_ + w0 + 4 * dcc] = st;
        }
        __syncthreads();   // stage reused next nt
    }
}

// ---------------------------------------------------------------------------
// fc_mfma_k: per-unit FC1 via MFMA + BN2+ReLU+FC2+BN3+ReLU -> zT (B,304)
// 1-D grid 600, XCD-swizzled so both bt blocks of a unit share an XCD L2.
// 4 waves = 4 m-tiles x all 4 n-tiles. B: raw w_fc1 staged to LDS as bf16
// (unscaled); BN2 scale applied in f32 epilogue.
// ---------------------------------------------------------------------------
__global__ __launch_bounds__(256, 3)
void fc_mfma_k(const ushort_t* __restrict__ pooled,  // (U,B,P) bf16
               const float* __restrict__ w_fc1,      // (U,FC,P) f32
               const float* __restrict__ b_fc1,
               const float* __restrict__ g2,
               const float* __restrict__ be2,
               const float* __restrict__ m2,
               const float* __restrict__ v2,
               const float* __restrict__ w_fc2,
               const float* __restrict__ b_fc2,
               const float* __restrict__ g3,
               const float* __restrict__ be3,
               const float* __restrict__ m3,
               const float* __restrict__ v3,
               float* __restrict__ zT)               // (B,304)
{
    __shared__ ushort_t wlds[FC_ * WLD_];  // 100 rows x 144 bf16 = 28.8 KB
    __shared__ float zred[128][33];
    const int tid  = threadIdx.x;
    // XCD-swizzle decode: u<296: bid = (u%8) + 8*((u/8)*2 + bt); tail appended
    const int bid = blockIdx.x;
    int u, bt;
    if (bid < 592) {
        const int r = bid & 7, k = bid >> 3;
        bt = k & 1;
        u  = (k >> 1) * 8 + r;
    } else {
        const int t = bid - 592;
        u  = 296 + (t >> 1);
        bt = t & 1;
    }

    // stage raw w_fc1 panel -> bf16 LDS (coalesced float4 reads)
    const float* __restrict__ wsrc = w_fc1 + (size_t)u * FC_ * P_;
    for (int idx = tid; idx < FC_ * 35; idx += 256) {
        const int f = idx / 35, j = idx - f * 35;
        const float4 v = *(const float4*)(wsrc + f * P_ + 4 * j);
        ushort4 pk;
        pk.x = f2bf(v.x); pk.y = f2bf(v.y); pk.z = f2bf(v.z); pk.w = f2bf(v.w);
        *(ushort4*)&wlds[f * WLD_ + 4 * j] = pk;
    }
    for (int idx = tid; idx < FC_ * 4; idx += 256) {
        const int f = idx >> 2, k = 140 + (idx & 3);
        wlds[f * WLD_ + k] = 0;
    }
    __syncthreads();

    const int lane = tid & 63;
    const int wv   = tid >> 6;            // m-tile within the 128-batch panel
    const int half = lane >> 5;
    const int r32  = lane & 31;

    const int brow = bt * 128 + wv * 32 + r32;
    const ushort_t* __restrict__ abase =
        pooled + ((size_t)u * B_ + brow) * P_ + half * 8;

    const ushort_t* __restrict__ bl0 = &wlds[r32 * WLD_ + half * 8];
    const ushort_t* __restrict__ bl1 = &wlds[(32 + r32) * WLD_ + half * 8];
    const ushort_t* __restrict__ bl2 = &wlds[(64 + r32) * WLD_ + half * 8];
    const int f3c = (96 + r32 < FC_) ? (96 + r32) : (FC_ - 1);   // clamp
    const ushort_t* __restrict__ bl3 = &wlds[f3c * WLD_ + half * 8];

    // A software-pipelined; B from LDS (low latency)
    short8v ac = *(const short8v*)(abase);
    f32x16 acc0 = {}, acc1 = {}, acc2 = {}, acc3 = {};
#pragma unroll
    for (int kc = 0; kc < 9; ++kc) {
        const int kn = (kc < 8) ? kc + 1 : kc;
        const short8v an = *(const short8v*)(abase + kn * 16);
        const short8v b0 = *(const short8v*)(bl0 + kc * 16);
        const short8v b1 = *(const short8v*)(bl1 + kc * 16);
        const short8v b2 = *(const short8v*)(bl2 + kc * 16);
        const short8v b3 = *(const short8v*)(bl3 + kc * 16);
        acc0 = __builtin_amdgcn_mfma_f32_32x32x16_bf16(ac, b0, acc0, 0, 0, 0);
        acc1 = __builtin_amdgcn_mfma_f32_32x32x16_bf16(ac, b1, acc1, 0, 0, 0);
        acc2 = __builtin_amdgcn_mfma_f32_32x32x16_bf16(ac, b2, acc2, 0, 0, 0);
        acc3 = __builtin_amdgcn_mfma_f32_32x32x16_bf16(ac, b3, acc3, 0, 0, 0);
        ac = an;
    }

    // inline BN2 params per lane (4 f-columns)
    float s2[4], o2[4], w2[4];
#pragma unroll
    for (int n = 0; n < 4; ++n) {
        const int f = n * 32 + r32;
        if (f < FC_) {
            const int fg = u * FC_ + f;
            const float ss = g2[fg] / sqrtf(v2[fg] + EPS_);
            s2[n] = ss;
            o2[n] = (b_fc1[fg] - m2[fg]) * ss + be2[fg];
            w2[n] = w_fc2[fg];
        } else {
            s2[n] = 0.f; o2[n] = 0.f; w2[n] = 0.f;
        }
    }
#pragma unroll
    for (int rg = 0; rg < 16; ++rg) {
        const int row = (rg & 3) + 8 * (rg >> 2) + 4 * half;
        float s = fmaxf(fmaf(acc0[rg], s2[0], o2[0]), 0.f) * w2[0];
        s = fmaf(fmaxf(fmaf(acc1[rg], s2[1], o2[1]), 0.f), w2[1], s);
        s = fmaf(fmaxf(fmaf(acc2[rg], s2[2], o2[2]), 0.f), w2[2], s);
        s = fmaf(fmaxf(fmaf(acc3[rg], s2[3], o2[3]), 0.f), w2[3], s);
        zred[wv * 32 + row][r32] = s;
    }
    __syncthreads();

    // reduce 32 lane-partials per batch row; write transposed (B,304)
    if (tid < 128) {
        float s = 0.f;
#pragma unroll
        for (int j = 0; j < 32; ++j) s += zred[tid][j];
        const float s3 = g3[u] / sqrtf(v3[u] + EPS_);
        const float o3 = (b_fc2[u] - m3[u]) * s3 + be3[u];
        zT[(size_t)(bt * 128 + tid) * 304 + u] = fmaxf(fmaf(s, s3, o3), 0.f);
    }
}

// ---------------------------------------------------------------------------
// out_k: out[b] = sigmoid( dot(zT[b,0:300], w_out) + b_out ), coalesced f4.
// ---------------------------------------------------------------------------
__global__ __launch_bounds__(64, 8)
void out_k(const float* __restrict__ zT,      // (B,304)
           const float* __restrict__ w_out,   // (U,1)
           const float* __restrict__ b_out,   // (1,)
           float* __restrict__ out)           // (B,1)
{
    const int lane = threadIdx.x;
    const int b    = blockIdx.x;
    const float4* zr = (const float4*)(zT + (size_t)b * 304);
    const float4* w4 = (const float4*)w_out;

    float s = 0.f;
    for (int i = lane; i < 75; i += 64) {
        const float4 z = zr[i], w = w4[i];
        s += z.x * w.x + z.y * w.y + z.z * w.z + z.w * w.w;
    }
#pragma unroll
    for (int o = 32; o > 0; o >>= 1) s += __shfl_xor(s, o);
    if (lane == 0)
        out[b] = 1.0f / (1.0f + __expf(-(s + b_out[0])));
}

// ---------------------------------------------------------------------------
extern "C" void kernel_launch(void* const* d_in, const int* in_sizes, int n_in,
                              void* d_out, int out_size, void* d_ws, size_t ws_size,
                              hipStream_t stream)
{
    const float* input_seq = (const float*)d_in[0];   // (B,L,4)
    const float* w_conv    = (const float*)d_in[1];
    const float* b_conv    = (const float*)d_in[2];
    const float* g1        = (const float*)d_in[3];
    const float* be1       = (const float*)d_in[4];
    const float* m1        = (const float*)d_in[5];
    const float* v1        = (const float*)d_in[6];
    const float* w_fc1     = (const float*)d_in[7];
    const float* b_fc1     = (const float*)d_in[8];
    const float* g2        = (const float*)d_in[9];
    const float* be2       = (const float*)d_in[10];
    const float* m2        = (const float*)d_in[11];
    const float* v2        = (const float*)d_in[12];
    const float* w_fc2     = (const float*)d_in[13];
    const float* b_fc2     = (const float*)d_in[14];
    const float* g3        = (const float*)d_in[15];
    const float* be3       = (const float*)d_in[16];
    const float* m3        = (const float*)d_in[17];
    const float* v3        = (const float*)d_in[18];
    const float* w_out     = (const float*)d_in[19];
    const float* b_out     = (const float*)d_in[20];

    // Workspace layout (~21.9 MB of ws):
    char* p = (char*)d_ws;
    ushort_t* pooled = (ushort_t*)p;   p += (size_t)B_ * U_ * P_ * 2;   // 21,504,000
    ushort_t* w_bf   = (ushort_t*)p;   p += 320 * 80 * 2;               //     51,200
    float*    o1g    = (float*)p;      p += 320 * 4;                    //      1,280
    float*    zT     = (float*)p;      p += (size_t)B_ * 304 * 4;       //    311,296

    pack_conv_k<<<dim3(100), 256, 0, stream>>>(
        w_conv, b_conv, g1, be1, m1, v1, w_bf, o1g);

    conv_mfma_k<<<dim3(5, 128), 448, 0, stream>>>(
        (const float4*)input_seq, w_bf, o1g, pooled);

    fc_mfma_k<<<dim3(600), 256, 0, stream>>>(
        pooled, w_fc1, b_fc1, g2, be2, m2, v2, w_fc2, b_fc2,
        g3, be3, m3, v3, zT);

    out_k<<<dim3(B_), 64, 0, stream>>>(zT, w_out, b_out, (float*)d_out);
}

// Round 16
// 55.100 us; speedup vs baseline: 1.1759x; 1.0124x over previous
//
#include <hip/hip_runtime.h>
#include <hip/hip_bf16.h>
#include <math.h>

// Problem constants
#define U_   300
#define K_   19
#define FC_  100
#define B_   256
#define L_   1000
#define P_   140     // pooled length
#define EPS_ 1e-5f
#define WLD_ 144     // fc LDS row stride (bf16): 288 B, 16-B aligned

typedef unsigned short ushort_t;
typedef __attribute__((ext_vector_type(8)))  short short8v;   // 8 bf16 = 4 VGPR
typedef __attribute__((ext_vector_type(16))) float f32x16;    // MFMA 32x32 acc

// f32 -> bf16 round-to-nearest-even (bit trick)
__device__ __forceinline__ ushort_t f2bf(float f) {
    union { float f; unsigned u; } a; a.f = f;
    unsigned r = a.u + 0x7fffu + ((a.u >> 16) & 1u);
    return (ushort_t)(r >> 16);
}

// ---------------------------------------------------------------------------
// pack_conv_k: conv weights -> bf16, BN1 scale folded, LANE-LINEAR tile layout:
//   element offset = nt*2560 + kc*512 + half*256 + r*8 + e
// (u = nt*32 + r, GEMM-k j = kc*16 + half*8 + e, j order = 4*t + d).
// MFMA lane (half*32+r) reads its 16 B at byte offset lane*16 within the
// (nt,kc) 1-KB slab -> linear ds_read_b128, conflict-free.
// ---------------------------------------------------------------------------
__global__ __launch_bounds__(256, 4)
void pack_conv_k(const float* __restrict__ w_conv, const float* __restrict__ b_conv,
                 const float* __restrict__ g1, const float* __restrict__ be1,
                 const float* __restrict__ m1, const float* __restrict__ v1,
                 ushort_t* __restrict__ w_bf, float* __restrict__ o1g)
{
    const int t = blockIdx.x * 256 + threadIdx.x;
    if (t < 320 * 80) {
        const int u = t / 80, j = t - u * 80;
        float val = 0.f;
        if (u < U_ && j < 76) {
            const int tp = j >> 2;          // kernel position 0..18
            const int d  = j & 3;           // DNA channel 0..3
            const float s1 = g1[u] / sqrtf(v1[u] + EPS_);
            val = w_conv[u * 76 + 19 * d + tp] * s1;
        }
        const int nt = u >> 5, r = u & 31;
        const int kc = j >> 4, rem = j & 15;
        const int half = rem >> 3, e = rem & 7;
        w_bf[nt * 2560 + kc * 512 + half * 256 + r * 8 + e] = f2bf(val);
    }
    if (t < 320) {
        float o = 0.f;
        if (t < U_) {
            const float s1 = g1[t] / sqrtf(v1[t] + EPS_);
            o = (b_conv[t] - m1[t]) * s1 + be1[t];
        }
        o1g[t] = o;
    }
}

// ---------------------------------------------------------------------------
// conv_mfma_k: implicit-GEMM conv + BN1 + maxpool + exp.
// ROUND-16 CHANGE: barrier-free compute phase. Weight table (51.2 KB) + x
// (1.76 KB) + o1 in LDS; compute loop nt=0..9 has NO __syncthreads -- each
// nt: 5 ds_read_b128 (B), 5 MFMA (fresh acc -> independent chains, compiler
// pipelines across nt), in-register pooling, exp, 2 ds_write_b16 into a
// one-shot [320][30] stage. ONE barrier, then coalesced drain (7 lanes = 56
// contiguous B per u-row). Previous structure had 20 barriers/block -- the
// wave-lockstep serialization that kept conv at ~35us over 8 variants.
// One batch per block; 448 threads = 7 waves = 7 m-tiles (4 windows each).
// ---------------------------------------------------------------------------
__global__ __launch_bounds__(448, 4)
void conv_mfma_k(const float4* __restrict__ x4,        // (B,1000) float4 (D=4)
                 const ushort_t* __restrict__ w_bf,    // packed tiles (see pack)
                 const float* __restrict__ o1g,        // (320)
                 ushort_t* __restrict__ pooled)        // (U,B,P) bf16
{
    __shared__ ushort_t xls[880];        // bf16 x_flat rows l0..l0+219
    __shared__ ushort_t wlds[25600];     // full packed weight table, 51.2 KB
    __shared__ float    o1l[320];
    __shared__ ushort_t stage[320][30];  // [u][p-local], stride 15 words (odd)
    const int tid = threadIdx.x;
    const int bx  = blockIdx.x;          // 0..4
    const int b   = blockIdx.y;
    const int w0  = bx * 28;             // first window of block
    const int l0  = w0 * 7;              // first conv row (bx*196, max 784)

    // stage x rows as bf16
    if (tid < 220) {
        const int gi = l0 + tid;
        float4 v = make_float4(0.f, 0.f, 0.f, 0.f);
        if (gi < L_) v = x4[(size_t)b * L_ + gi];
        ushort4 pk4;
        pk4.x = f2bf(v.x); pk4.y = f2bf(v.y); pk4.z = f2bf(v.z); pk4.w = f2bf(v.w);
        *(ushort4*)&xls[4 * tid] = pk4;
    }
    // stage full weight table + o1 into LDS (coalesced 16-B chunks)
    {
        const float4* ws = (const float4*)w_bf;
        float4* wd = (float4*)wlds;
        for (int i = tid; i < 3200; i += 448) wd[i] = ws[i];
        if (tid < 320) o1l[tid] = o1g[tid];
    }
    __syncthreads();

    const int lane = tid & 63;
    const int mt   = tid >> 6;           // m-tile 0..6
    const int half = lane >> 5;
    const int r32  = lane & 31;

    // permuted A-row offset for slot r32
    const int sreg = (r32 & 3) + 4 * (r32 >> 3);
    const int sh   = (r32 >> 2) & 1;
    const int off  = sreg < 7  ? sreg + 7 * sh
                   : sreg < 14 ? sreg + 7 + 7 * sh
                               : 28 + (sreg - 14) + 2 * sh;

    const char* xb = (const char*)xls + 8 * (28 * mt + off) + 16 * half;
    const char* wl = (const char*)wlds + 16 * lane;   // lane-linear B base

    // hoist nt-invariant A-fragments into registers
    short8v aA[5];
#pragma unroll
    for (int kc = 0; kc < 5; ++kc)
        aA[kc] = *(const short8v*)(xb + 32 * kc);

    const int pcol = 4 * mt + half;      // stage columns pcol, pcol+2

    // barrier-free compute: 10 independent nt iterations
#pragma unroll
    for (int nt = 0; nt < 10; ++nt) {
        short8v bfr[5];
#pragma unroll
        for (int kc = 0; kc < 5; ++kc)
            bfr[kc] = *(const short8v*)(wl + nt * 5120 + kc * 1024);
        const float o1u = o1l[nt * 32 + r32];

        f32x16 acc = {};
#pragma unroll
        for (int kc = 0; kc < 5; ++kc)
            acc = __builtin_amdgcn_mfma_f32_32x32x16_bf16(aA[kc], bfr[kc], acc, 0, 0, 0);

        // in-register pooling (o1 added after max; exp monotone)
        float m0 = acc[0], m1 = acc[7];
#pragma unroll
        for (int j = 1; j < 7; ++j)  m0 = fmaxf(m0, acc[j]);
#pragma unroll
        for (int j = 8; j < 14; ++j) m1 = fmaxf(m1, acc[j]);

        stage[nt * 32 + r32][pcol]     = f2bf(__expf(m0 + o1u));
        stage[nt * 32 + r32][pcol + 2] = f2bf(__expf(m1 + o1u));
    }
    __syncthreads();

    // coalesced drain: 2240 ushort4 chunks (320 rows x 7), 5 per thread
#pragma unroll
    for (int i = 0; i < 5; ++i) {
        const int idx = tid + 448 * i;
        const int row = idx / 7;         // u
        const int cc  = idx - 7 * row;
        if (row < U_) {
            const ushort4 st = *(const ushort4*)&stage[row][4 * cc];
            *(ushort4*)&pooled[((size_t)row * B_ + b) * P_ + w0 + 4 * cc] = st;
        }
    }
}

// ---------------------------------------------------------------------------
// fc_mfma_k: per-unit FC1 via MFMA + BN2+ReLU+FC2+BN3+ReLU -> zT (B,304)
// 1-D grid 600, XCD-swizzled so both bt blocks of a unit share an XCD L2.
// 4 waves = 4 m-tiles x all 4 n-tiles. B: raw w_fc1 staged to LDS as bf16
// (unscaled); BN2 scale applied in f32 epilogue.
// ---------------------------------------------------------------------------
__global__ __launch_bounds__(256, 3)
void fc_mfma_k(const ushort_t* __restrict__ pooled,  // (U,B,P) bf16
               const float* __restrict__ w_fc1,      // (U,FC,P) f32
               const float* __restrict__ b_fc1,
               const float* __restrict__ g2,
               const float* __restrict__ be2,
               const float* __restrict__ m2,
               const float* __restrict__ v2,
               const float* __restrict__ w_fc2,
               const float* __restrict__ b_fc2,
               const float* __restrict__ g3,
               const float* __restrict__ be3,
               const float* __restrict__ m3,
               const float* __restrict__ v3,
               float* __restrict__ zT)               // (B,304)
{
    __shared__ ushort_t wlds[FC_ * WLD_];  // 100 rows x 144 bf16 = 28.8 KB
    __shared__ float zred[128][33];
    const int tid  = threadIdx.x;
    // XCD-swizzle decode: u<296: bid = (u%8) + 8*((u/8)*2 + bt); tail appended
    const int bid = blockIdx.x;
    int u, bt;
    if (bid < 592) {
        const int r = bid & 7, k = bid >> 3;
        bt = k & 1;
        u  = (k >> 1) * 8 + r;
    } else {
        const int t = bid - 592;
        u  = 296 + (t >> 1);
        bt = t & 1;
    }

    // stage raw w_fc1 panel -> bf16 LDS (coalesced float4 reads)
    const float* __restrict__ wsrc = w_fc1 + (size_t)u * FC_ * P_;
    for (int idx = tid; idx < FC_ * 35; idx += 256) {
        const int f = idx / 35, j = idx - f * 35;
        const float4 v = *(const float4*)(wsrc + f * P_ + 4 * j);
        ushort4 pk;
        pk.x = f2bf(v.x); pk.y = f2bf(v.y); pk.z = f2bf(v.z); pk.w = f2bf(v.w);
        *(ushort4*)&wlds[f * WLD_ + 4 * j] = pk;
    }
    for (int idx = tid; idx < FC_ * 4; idx += 256) {
        const int f = idx >> 2, k = 140 + (idx & 3);
        wlds[f * WLD_ + k] = 0;
    }
    __syncthreads();

    const int lane = tid & 63;
    const int wv   = tid >> 6;            // m-tile within the 128-batch panel
    const int half = lane >> 5;
    const int r32  = lane & 31;

    const int brow = bt * 128 + wv * 32 + r32;
    const ushort_t* __restrict__ abase =
        pooled + ((size_t)u * B_ + brow) * P_ + half * 8;

    const ushort_t* __restrict__ bl0 = &wlds[r32 * WLD_ + half * 8];
    const ushort_t* __restrict__ bl1 = &wlds[(32 + r32) * WLD_ + half * 8];
    const ushort_t* __restrict__ bl2 = &wlds[(64 + r32) * WLD_ + half * 8];
    const int f3c = (96 + r32 < FC_) ? (96 + r32) : (FC_ - 1);   // clamp
    const ushort_t* __restrict__ bl3 = &wlds[f3c * WLD_ + half * 8];

    // A software-pipelined; B from LDS (low latency)
    short8v ac = *(const short8v*)(abase);
    f32x16 acc0 = {}, acc1 = {}, acc2 = {}, acc3 = {};
#pragma unroll
    for (int kc = 0; kc < 9; ++kc) {
        const int kn = (kc < 8) ? kc + 1 : kc;
        const short8v an = *(const short8v*)(abase + kn * 16);
        const short8v b0 = *(const short8v*)(bl0 + kc * 16);
        const short8v b1 = *(const short8v*)(bl1 + kc * 16);
        const short8v b2 = *(const short8v*)(bl2 + kc * 16);
        const short8v b3 = *(const short8v*)(bl3 + kc * 16);
        acc0 = __builtin_amdgcn_mfma_f32_32x32x16_bf16(ac, b0, acc0, 0, 0, 0);
        acc1 = __builtin_amdgcn_mfma_f32_32x32x16_bf16(ac, b1, acc1, 0, 0, 0);
        acc2 = __builtin_amdgcn_mfma_f32_32x32x16_bf16(ac, b2, acc2, 0, 0, 0);
        acc3 = __builtin_amdgcn_mfma_f32_32x32x16_bf16(ac, b3, acc3, 0, 0, 0);
        ac = an;
    }

    // inline BN2 params per lane (4 f-columns)
    float s2[4], o2[4], w2[4];
#pragma unroll
    for (int n = 0; n < 4; ++n) {
        const int f = n * 32 + r32;
        if (f < FC_) {
            const int fg = u * FC_ + f;
            const float ss = g2[fg] / sqrtf(v2[fg] + EPS_);
            s2[n] = ss;
            o2[n] = (b_fc1[fg] - m2[fg]) * ss + be2[fg];
            w2[n] = w_fc2[fg];
        } else {
            s2[n] = 0.f; o2[n] = 0.f; w2[n] = 0.f;
        }
    }
#pragma unroll
    for (int rg = 0; rg < 16; ++rg) {
        const int row = (rg & 3) + 8 * (rg >> 2) + 4 * half;
        float s = fmaxf(fmaf(acc0[rg], s2[0], o2[0]), 0.f) * w2[0];
        s = fmaf(fmaxf(fmaf(acc1[rg], s2[1], o2[1]), 0.f), w2[1], s);
        s = fmaf(fmaxf(fmaf(acc2[rg], s2[2], o2[2]), 0.f), w2[2], s);
        s = fmaf(fmaxf(fmaf(acc3[rg], s2[3], o2[3]), 0.f), w2[3], s);
        zred[wv * 32 + row][r32] = s;
    }
    __syncthreads();

    // reduce 32 lane-partials per batch row; write transposed (B,304)
    if (tid < 128) {
        float s = 0.f;
#pragma unroll
        for (int j = 0; j < 32; ++j) s += zred[tid][j];
        const float s3 = g3[u] / sqrtf(v3[u] + EPS_);
        const float o3 = (b_fc2[u] - m3[u]) * s3 + be3[u];
        zT[(size_t)(bt * 128 + tid) * 304 + u] = fmaxf(fmaf(s, s3, o3), 0.f);
    }
}

// ---------------------------------------------------------------------------
// out_k: out[b] = sigmoid( dot(zT[b,0:300], w_out) + b_out ), coalesced f4.
// ---------------------------------------------------------------------------
__global__ __launch_bounds__(64, 8)
void out_k(const float* __restrict__ zT,      // (B,304)
           const float* __restrict__ w_out,   // (U,1)
           const float* __restrict__ b_out,   // (1,)
           float* __restrict__ out)           // (B,1)
{
    const int lane = threadIdx.x;
    const int b    = blockIdx.x;
    const float4* zr = (const float4*)(zT + (size_t)b * 304);
    const float4* w4 = (const float4*)w_out;

    float s = 0.f;
    for (int i = lane; i < 75; i += 64) {
        const float4 z = zr[i], w = w4[i];
        s += z.x * w.x + z.y * w.y + z.z * w.z + z.w * w.w;
    }
#pragma unroll
    for (int o = 32; o > 0; o >>= 1) s += __shfl_xor(s, o);
    if (lane == 0)
        out[b] = 1.0f / (1.0f + __expf(-(s + b_out[0])));
}

// ---------------------------------------------------------------------------
extern "C" void kernel_launch(void* const* d_in, const int* in_sizes, int n_in,
                              void* d_out, int out_size, void* d_ws, size_t ws_size,
                              hipStream_t stream)
{
    const float* input_seq = (const float*)d_in[0];   // (B,L,4)
    const float* w_conv    = (const float*)d_in[1];
    const float* b_conv    = (const float*)d_in[2];
    const float* g1        = (const float*)d_in[3];
    const float* be1       = (const float*)d_in[4];
    const float* m1        = (const float*)d_in[5];
    const float* v1        = (const float*)d_in[6];
    const float* w_fc1     = (const float*)d_in[7];
    const float* b_fc1     = (const float*)d_in[8];
    const float* g2        = (const float*)d_in[9];
    const float* be2       = (const float*)d_in[10];
    const float* m2        = (const float*)d_in[11];
    const float* v2        = (const float*)d_in[12];
    const float* w_fc2     = (const float*)d_in[13];
    const float* b_fc2     = (const float*)d_in[14];
    const float* g3        = (const float*)d_in[15];
    const float* be3       = (const float*)d_in[16];
    const float* m3        = (const float*)d_in[17];
    const float* v3        = (const float*)d_in[18];
    const float* w_out     = (const float*)d_in[19];
    const float* b_out     = (const float*)d_in[20];

    // Workspace layout (~21.9 MB of ws):
    char* p = (char*)d_ws;
    ushort_t* pooled = (ushort_t*)p;   p += (size_t)B_ * U_ * P_ * 2;   // 21,504,000
    ushort_t* w_bf   = (ushort_t*)p;   p += 320 * 80 * 2;               //     51,200
    float*    o1g    = (float*)p;      p += 320 * 4;                    //      1,280
    float*    zT     = (float*)p;      p += (size_t)B_ * 304 * 4;       //    311,296

    pack_conv_k<<<dim3(100), 256, 0, stream>>>(
        w_conv, b_conv, g1, be1, m1, v1, w_bf, o1g);

    conv_mfma_k<<<dim3(5, B_), 448, 0, stream>>>(
        (const float4*)input_seq, w_bf, o1g, pooled);

    fc_mfma_k<<<dim3(600), 256, 0, stream>>>(
        pooled, w_fc1, b_fc1, g2, be2, m2, v2, w_fc2, b_fc2,
        g3, be3, m3, v3, zT);

    out_k<<<dim3(B_), 64, 0, stream>>>(zT, w_out, b_out, (float*)d_out);
}

// Round 17
// 54.821 us; speedup vs baseline: 1.1819x; 1.0051x over previous
//
#include <hip/hip_runtime.h>
#include <hip/hip_bf16.h>
#include <math.h>

// Problem constants
#define U_   300
#define K_   19
#define FC_  100
#define B_   256
#define L_   1000
#define P_   140     // pooled length
#define EPS_ 1e-5f
#define WLD_ 144     // fc LDS row stride (bf16): 288 B, 16-B aligned

typedef unsigned short ushort_t;
typedef __attribute__((ext_vector_type(8)))  short short8v;   // 8 bf16 = 4 VGPR
typedef __attribute__((ext_vector_type(16))) float f32x16;    // MFMA 32x32 acc

// f32 -> bf16 round-to-nearest-even (bit trick)
__device__ __forceinline__ ushort_t f2bf(float f) {
    union { float f; unsigned u; } a; a.f = f;
    unsigned r = a.u + 0x7fffu + ((a.u >> 16) & 1u);
    return (ushort_t)(r >> 16);
}

// ---------------------------------------------------------------------------
// pack_conv_k: conv weights -> bf16, BN1 scale folded, LANE-LINEAR tile layout:
//   element offset = nt*2560 + kc*512 + half*256 + r*8 + e
// (u = nt*32 + r, GEMM-k j = kc*16 + half*8 + e, j order = 4*t + d).
// MFMA lane (half*32+r) reads its 16 B at byte offset lane*16 within the
// (nt,kc) 1-KB slab -> linear ds_read_b128, conflict-free.
// ---------------------------------------------------------------------------
__global__ __launch_bounds__(256, 4)
void pack_conv_k(const float* __restrict__ w_conv, const float* __restrict__ b_conv,
                 const float* __restrict__ g1, const float* __restrict__ be1,
                 const float* __restrict__ m1, const float* __restrict__ v1,
                 ushort_t* __restrict__ w_bf, float* __restrict__ o1g)
{
    const int t = blockIdx.x * 256 + threadIdx.x;
    if (t < 320 * 80) {
        const int u = t / 80, j = t - u * 80;
        float val = 0.f;
        if (u < U_ && j < 76) {
            const int tp = j >> 2;          // kernel position 0..18
            const int d  = j & 3;           // DNA channel 0..3
            const float s1 = g1[u] / sqrtf(v1[u] + EPS_);
            val = w_conv[u * 76 + 19 * d + tp] * s1;
        }
        const int nt = u >> 5, r = u & 31;
        const int kc = j >> 4, rem = j & 15;
        const int half = rem >> 3, e = rem & 7;
        w_bf[nt * 2560 + kc * 512 + half * 256 + r * 8 + e] = f2bf(val);
    }
    if (t < 320) {
        float o = 0.f;
        if (t < U_) {
            const float s1 = g1[t] / sqrtf(v1[t] + EPS_);
            o = (b_conv[t] - m1[t]) * s1 + be1[t];
        }
        o1g[t] = o;
    }
}

// ---------------------------------------------------------------------------
// conv_mfma_k: implicit-GEMM conv + BN1 + maxpool + exp.
// ROUND-17 CHANGE: occupancy. LDS footprint cut 73.4 -> ~33.5 KB by splitting
// the n-dim across blocks (nh = 0/1, 5 nt-tiles each; only half the weight
// table staged per block) -> 4 blocks/CU = 28 waves/CU (vs 2 blocks, 44%).
// Stage stalls of one block now overlap compute of three others.
// Dual-batch per block: two independent MFMA chains share B-frags (ILP).
// 448 threads = 7 waves = 7 m-tiles (4 windows each; 5 bx x 28 = 140 exact).
// In-register pooling via per-tile row permutation; per-nt LDS stage +
// coalesced drain (7 lanes = 56 contiguous B per u-row).
// ---------------------------------------------------------------------------
__global__ __launch_bounds__(448, 4)
void conv_mfma_k(const float4* __restrict__ x4,        // (B,1000) float4 (D=4)
                 const ushort_t* __restrict__ w_bf,    // packed tiles (see pack)
                 const float* __restrict__ o1g,        // (320)
                 ushort_t* __restrict__ pooled)        // (U,B,P) bf16
{
    __shared__ ushort_t xls[2][880];     // bf16 x_flat rows l0..l0+219, 2 batches
    __shared__ ushort_t wlds[12800];     // HALF weight table (5 nt), 25.6 KB
    __shared__ ushort_t stage[32][68];   // [u-local][b*32 + p-local]
    const int tid = threadIdx.x;
    const int bx  = blockIdx.x;          // 0..4
    const int nh  = blockIdx.y;          // 0/1 -> nt range [5nh, 5nh+5)
    const int b0  = 2 * blockIdx.z;      // batches b0, b0+1
    const int w0  = bx * 28;             // first window of block
    const int l0  = w0 * 7;              // first conv row (bx*196, max 784)

    // stage x rows (both batches) as bf16
    if (tid < 440) {
        const int which = (tid >= 220) ? 1 : 0;
        const int i = tid - 220 * which;
        const int gi = l0 + i;
        float4 v = make_float4(0.f, 0.f, 0.f, 0.f);
        if (gi < L_) v = x4[(size_t)(b0 + which) * L_ + gi];
        ushort4 pk4;
        pk4.x = f2bf(v.x); pk4.y = f2bf(v.y); pk4.z = f2bf(v.z); pk4.w = f2bf(v.w);
        *(ushort4*)&xls[which][4 * i] = pk4;
    }
    // stage this block's half of the weight table (1600 float4)
    {
        const float4* ws = (const float4*)w_bf + nh * 1600;
        float4* wd = (float4*)wlds;
        for (int i = tid; i < 1600; i += 448) wd[i] = ws[i];
    }
    __syncthreads();

    const int lane = tid & 63;
    const int mt   = tid >> 6;           // m-tile 0..6
    const int half = lane >> 5;
    const int r32  = lane & 31;

    // permuted A-row offset for slot r32
    const int sreg = (r32 & 3) + 4 * (r32 >> 3);
    const int sh   = (r32 >> 2) & 1;
    const int off  = sreg < 7  ? sreg + 7 * sh
                   : sreg < 14 ? sreg + 7 + 7 * sh
                               : 28 + (sreg - 14) + 2 * sh;

    const char* xb0 = (const char*)&xls[0][0] + 8 * (28 * mt + off) + 16 * half;
    const char* xb1 = xb0 + 1760;        // xls[1] is 880 ushorts later
    const char* wl  = (const char*)wlds + 16 * lane;   // lane-linear B base

    // hoist nt-invariant A-fragments (both batches) into registers
    short8v aA0[5], aA1[5];
#pragma unroll
    for (int kc = 0; kc < 5; ++kc) {
        aA0[kc] = *(const short8v*)(xb0 + 32 * kc);
        aA1[kc] = *(const short8v*)(xb1 + 32 * kc);
    }

    // drain mapping: thread -> (u-local, b-local, 4-window chunk)
    const int dr  = tid / 7;             // 0..63
    const int dcc = tid - 7 * dr;        // 0..6
    const int dul = dr >> 1;             // u-local 0..31
    const int dbl = dr & 1;              // batch-local

    // stage indices this lane writes: poff = 4*mt + {half, 2+half}
    const int p0off = 4 * mt + half;

    for (int ntp = 0; ntp < 5; ++ntp) {
        short8v bfr[5];
#pragma unroll
        for (int kc = 0; kc < 5; ++kc)
            bfr[kc] = *(const short8v*)(wl + ntp * 5120 + kc * 1024);
        const float o1u = o1g[nh * 160 + ntp * 32 + r32];

        f32x16 acc0 = {};
        f32x16 acc1 = {};
#pragma unroll
        for (int kc = 0; kc < 5; ++kc) {
            acc0 = __builtin_amdgcn_mfma_f32_32x32x16_bf16(aA0[kc], bfr[kc], acc0, 0, 0, 0);
            acc1 = __builtin_amdgcn_mfma_f32_32x32x16_bf16(aA1[kc], bfr[kc], acc1, 0, 0, 0);
        }

        // in-register pooling for both batches (o1 added after max; exp monotone)
        float m00 = acc0[0], m01 = acc0[7];
        float m10 = acc1[0], m11 = acc1[7];
#pragma unroll
        for (int j = 1; j < 7; ++j)  { m00 = fmaxf(m00, acc0[j]); m10 = fmaxf(m10, acc1[j]); }
#pragma unroll
        for (int j = 8; j < 14; ++j) { m01 = fmaxf(m01, acc0[j]); m11 = fmaxf(m11, acc1[j]); }

        // LDS stage (2-way bank aliasing, free)
        stage[r32][p0off]          = f2bf(__expf(m00 + o1u));   // b0, window 4mt+half
        stage[r32][p0off + 2]      = f2bf(__expf(m01 + o1u));   // b0, window 4mt+2+half
        stage[r32][32 + p0off]     = f2bf(__expf(m10 + o1u));   // b1
        stage[r32][32 + p0off + 2] = f2bf(__expf(m11 + o1u));
        __syncthreads();

        // coalesced drain: 448 threads = 64 rows x 7 ushort4 chunks
        const int ug = nh * 160 + ntp * 32 + dul;
        if (ug < U_) {
            const ushort4 st = *(const ushort4*)&stage[dul][dbl * 32 + 4 * dcc];
            *(ushort4*)&pooled[((size_t)ug * B_ + (b0 + dbl)) * P_ + w0 + 4 * dcc] = st;
        }
        __syncthreads();   // stage reused next ntp
    }
}

// ---------------------------------------------------------------------------
// fc_mfma_k: per-unit FC1 via MFMA + BN2+ReLU+FC2+BN3+ReLU -> zT (B,304)
// 1-D grid 600, XCD-swizzled so both bt blocks of a unit share an XCD L2.
// 4 waves = 4 m-tiles x all 4 n-tiles. B: raw w_fc1 staged to LDS as bf16
// (unscaled); BN2 scale applied in f32 epilogue.
// ---------------------------------------------------------------------------
__global__ __launch_bounds__(256, 3)
void fc_mfma_k(const ushort_t* __restrict__ pooled,  // (U,B,P) bf16
               const float* __restrict__ w_fc1,      // (U,FC,P) f32
               const float* __restrict__ b_fc1,
               const float* __restrict__ g2,
               const float* __restrict__ be2,
               const float* __restrict__ m2,
               const float* __restrict__ v2,
               const float* __restrict__ w_fc2,
               const float* __restrict__ b_fc2,
               const float* __restrict__ g3,
               const float* __restrict__ be3,
               const float* __restrict__ m3,
               const float* __restrict__ v3,
               float* __restrict__ zT)               // (B,304)
{
    __shared__ ushort_t wlds[FC_ * WLD_];  // 100 rows x 144 bf16 = 28.8 KB
    __shared__ float zred[128][33];
    const int tid  = threadIdx.x;
    // XCD-swizzle decode: u<296: bid = (u%8) + 8*((u/8)*2 + bt); tail appended
    const int bid = blockIdx.x;
    int u, bt;
    if (bid < 592) {
        const int r = bid & 7, k = bid >> 3;
        bt = k & 1;
        u  = (k >> 1) * 8 + r;
    } else {
        const int t = bid - 592;
        u  = 296 + (t >> 1);
        bt = t & 1;
    }

    // stage raw w_fc1 panel -> bf16 LDS (coalesced float4 reads)
    const float* __restrict__ wsrc = w_fc1 + (size_t)u * FC_ * P_;
    for (int idx = tid; idx < FC_ * 35; idx += 256) {
        const int f = idx / 35, j = idx - f * 35;
        const float4 v = *(const float4*)(wsrc + f * P_ + 4 * j);
        ushort4 pk;
        pk.x = f2bf(v.x); pk.y = f2bf(v.y); pk.z = f2bf(v.z); pk.w = f2bf(v.w);
        *(ushort4*)&wlds[f * WLD_ + 4 * j] = pk;
    }
    for (int idx = tid; idx < FC_ * 4; idx += 256) {
        const int f = idx >> 2, k = 140 + (idx & 3);
        wlds[f * WLD_ + k] = 0;
    }
    __syncthreads();

    const int lane = tid & 63;
    const int wv   = tid >> 6;            // m-tile within the 128-batch panel
    const int half = lane >> 5;
    const int r32  = lane & 31;

    const int brow = bt * 128 + wv * 32 + r32;
    const ushort_t* __restrict__ abase =
        pooled + ((size_t)u * B_ + brow) * P_ + half * 8;

    const ushort_t* __restrict__ bl0 = &wlds[r32 * WLD_ + half * 8];
    const ushort_t* __restrict__ bl1 = &wlds[(32 + r32) * WLD_ + half * 8];
    const ushort_t* __restrict__ bl2 = &wlds[(64 + r32) * WLD_ + half * 8];
    const int f3c = (96 + r32 < FC_) ? (96 + r32) : (FC_ - 1);   // clamp
    const ushort_t* __restrict__ bl3 = &wlds[f3c * WLD_ + half * 8];

    // A software-pipelined; B from LDS (low latency)
    short8v ac = *(const short8v*)(abase);
    f32x16 acc0 = {}, acc1 = {}, acc2 = {}, acc3 = {};
#pragma unroll
    for (int kc = 0; kc < 9; ++kc) {
        const int kn = (kc < 8) ? kc + 1 : kc;
        const short8v an = *(const short8v*)(abase + kn * 16);
        const short8v b0 = *(const short8v*)(bl0 + kc * 16);
        const short8v b1 = *(const short8v*)(bl1 + kc * 16);
        const short8v b2 = *(const short8v*)(bl2 + kc * 16);
        const short8v b3 = *(const short8v*)(bl3 + kc * 16);
        acc0 = __builtin_amdgcn_mfma_f32_32x32x16_bf16(ac, b0, acc0, 0, 0, 0);
        acc1 = __builtin_amdgcn_mfma_f32_32x32x16_bf16(ac, b1, acc1, 0, 0, 0);
        acc2 = __builtin_amdgcn_mfma_f32_32x32x16_bf16(ac, b2, acc2, 0, 0, 0);
        acc3 = __builtin_amdgcn_mfma_f32_32x32x16_bf16(ac, b3, acc3, 0, 0, 0);
        ac = an;
    }

    // inline BN2 params per lane (4 f-columns)
    float s2[4], o2[4], w2[4];
#pragma unroll
    for (int n = 0; n < 4; ++n) {
        const int f = n * 32 + r32;
        if (f < FC_) {
            const int fg = u * FC_ + f;
            const float ss = g2[fg] / sqrtf(v2[fg] + EPS_);
            s2[n] = ss;
            o2[n] = (b_fc1[fg] - m2[fg]) * ss + be2[fg];
            w2[n] = w_fc2[fg];
        } else {
            s2[n] = 0.f; o2[n] = 0.f; w2[n] = 0.f;
        }
    }
#pragma unroll
    for (int rg = 0; rg < 16; ++rg) {
        const int row = (rg & 3) + 8 * (rg >> 2) + 4 * half;
        float s = fmaxf(fmaf(acc0[rg], s2[0], o2[0]), 0.f) * w2[0];
        s = fmaf(fmaxf(fmaf(acc1[rg], s2[1], o2[1]), 0.f), w2[1], s);
        s = fmaf(fmaxf(fmaf(acc2[rg], s2[2], o2[2]), 0.f), w2[2], s);
        s = fmaf(fmaxf(fmaf(acc3[rg], s2[3], o2[3]), 0.f), w2[3], s);
        zred[wv * 32 + row][r32] = s;
    }
    __syncthreads();

    // reduce 32 lane-partials per batch row; write transposed (B,304)
    if (tid < 128) {
        float s = 0.f;
#pragma unroll
        for (int j = 0; j < 32; ++j) s += zred[tid][j];
        const float s3 = g3[u] / sqrtf(v3[u] + EPS_);
        const float o3 = (b_fc2[u] - m3[u]) * s3 + be3[u];
        zT[(size_t)(bt * 128 + tid) * 304 + u] = fmaxf(fmaf(s, s3, o3), 0.f);
    }
}

// ---------------------------------------------------------------------------
// out_k: out[b] = sigmoid( dot(zT[b,0:300], w_out) + b_out ), coalesced f4.
// ---------------------------------------------------------------------------
__global__ __launch_bounds__(64, 8)
void out_k(const float* __restrict__ zT,      // (B,304)
           const float* __restrict__ w_out,   // (U,1)
           const float* __restrict__ b_out,   // (1,)
           float* __restrict__ out)           // (B,1)
{
    const int lane = threadIdx.x;
    const int b    = blockIdx.x;
    const float4* zr = (const float4*)(zT + (size_t)b * 304);
    const float4* w4 = (const float4*)w_out;

    float s = 0.f;
    for (int i = lane; i < 75; i += 64) {
        const float4 z = zr[i], w = w4[i];
        s += z.x * w.x + z.y * w.y + z.z * w.z + z.w * w.w;
    }
#pragma unroll
    for (int o = 32; o > 0; o >>= 1) s += __shfl_xor(s, o);
    if (lane == 0)
        out[b] = 1.0f / (1.0f + __expf(-(s + b_out[0])));
}

// ---------------------------------------------------------------------------
extern "C" void kernel_launch(void* const* d_in, const int* in_sizes, int n_in,
                              void* d_out, int out_size, void* d_ws, size_t ws_size,
                              hipStream_t stream)
{
    const float* input_seq = (const float*)d_in[0];   // (B,L,4)
    const float* w_conv    = (const float*)d_in[1];
    const float* b_conv    = (const float*)d_in[2];
    const float* g1        = (const float*)d_in[3];
    const float* be1       = (const float*)d_in[4];
    const float* m1        = (const float*)d_in[5];
    const float* v1        = (const float*)d_in[6];
    const float* w_fc1     = (const float*)d_in[7];
    const float* b_fc1     = (const float*)d_in[8];
    const float* g2        = (const float*)d_in[9];
    const float* be2       = (const float*)d_in[10];
    const float* m2        = (const float*)d_in[11];
    const float* v2        = (const float*)d_in[12];
    const float* w_fc2     = (const float*)d_in[13];
    const float* b_fc2     = (const float*)d_in[14];
    const float* g3        = (const float*)d_in[15];
    const float* be3       = (const float*)d_in[16];
    const float* m3        = (const float*)d_in[17];
    const float* v3        = (const float*)d_in[18];
    const float* w_out     = (const float*)d_in[19];
    const float* b_out     = (const float*)d_in[20];

    // Workspace layout (~21.9 MB of ws):
    char* p = (char*)d_ws;
    ushort_t* pooled = (ushort_t*)p;   p += (size_t)B_ * U_ * P_ * 2;   // 21,504,000
    ushort_t* w_bf   = (ushort_t*)p;   p += 320 * 80 * 2;               //     51,200
    float*    o1g    = (float*)p;      p += 320 * 4;                    //      1,280
    float*    zT     = (float*)p;      p += (size_t)B_ * 304 * 4;       //    311,296

    pack_conv_k<<<dim3(100), 256, 0, stream>>>(
        w_conv, b_conv, g1, be1, m1, v1, w_bf, o1g);

    conv_mfma_k<<<dim3(5, 2, 128), 448, 0, stream>>>(
        (const float4*)input_seq, w_bf, o1g, pooled);

    fc_mfma_k<<<dim3(600), 256, 0, stream>>>(
        pooled, w_fc1, b_fc1, g2, be2, m2, v2, w_fc2, b_fc2,
        g3, be3, m3, v3, zT);

    out_k<<<dim3(B_), 64, 0, stream>>>(zT, w_out, b_out, (float*)d_out);
}